// Round 1
// 469.344 us; speedup vs baseline: 1.0023x; 1.0023x over previous
//
#include <hip/hip_runtime.h>
#include <hip/hip_bf16.h>

typedef __attribute__((ext_vector_type(8))) short short8;
typedef __attribute__((ext_vector_type(4))) float f32x4;

#define S_DIM 384
#define N_DIM 512
#define C_DIM 32
#define CZ_DIM 128
#define MROWS (S_DIM * C_DIM) /* 12288 */

__device__ __forceinline__ void async16(const void* g, void* l) {
  __builtin_amdgcn_global_load_lds(
      (const __attribute__((address_space(1))) void*)g,
      (__attribute__((address_space(3))) void*)l, 16, 0, 0);
}

// Kernel 1: LayerNorm + w_ab projection.
// Emits A[(s*32+c)*512 + n] = a(s,n,c)/512 (bf16), B[(s*32+d)*512 + n] = b(s,n,d) (bf16).
__global__ __launch_bounds__(256) void prep_kernel(
    const float* __restrict__ m_si, const float* __restrict__ ln_g,
    const float* __restrict__ ln_b, const float* __restrict__ w_ab,
    __hip_bfloat16* __restrict__ Abt, __hip_bfloat16* __restrict__ Bbt) {
  const int n = blockIdx.x * 256 + threadIdx.x;  // 0..511
  const int s = blockIdx.y;                      // 0..383
  const float* x = m_si + ((size_t)s * N_DIM + n) * C_DIM;

  float v[C_DIM];
#pragma unroll
  for (int i = 0; i < 8; ++i) {
    float4 t = ((const float4*)x)[i];
    v[4 * i + 0] = t.x; v[4 * i + 1] = t.y;
    v[4 * i + 2] = t.z; v[4 * i + 3] = t.w;
  }
  float sum = 0.f;
#pragma unroll
  for (int c = 0; c < C_DIM; ++c) sum += v[c];
  const float mu = sum * (1.f / 32.f);
  float sq = 0.f;
#pragma unroll
  for (int c = 0; c < C_DIM; ++c) { float d = v[c] - mu; sq += d * d; }
  const float rstd = rsqrtf(sq * (1.f / 32.f) + 1e-5f);

  float mn[C_DIM];
#pragma unroll
  for (int c = 0; c < C_DIM; ++c)
    mn[c] = (v[c] - mu) * rstd * ln_g[c] + ln_b[c];

#pragma unroll 4
  for (int d = 0; d < 32; ++d) {
    float aA = 0.f, aB = 0.f;
#pragma unroll
    for (int c = 0; c < C_DIM; ++c) {
      aA += mn[c] * w_ab[d * C_DIM + c];          // uniform idx -> s_loads
      aB += mn[c] * w_ab[(d + 32) * C_DIM + c];
    }
    Abt[((size_t)(s * 32 + d)) * N_DIM + n] = __float2bfloat16(aA * (1.f / 512.f));
    Bbt[((size_t)(s * 32 + d)) * N_DIM + n] = __float2bfloat16(aB);
  }
}

// Kernel 2: w_final fp32 -> bf16 (128 x 1024)
__global__ __launch_bounds__(256) void conv_wf(const float* __restrict__ w_final,
                                               __hip_bfloat16* __restrict__ Wf) {
  const int i = blockIdx.x * 256 + threadIdx.x;
  Wf[i] = __float2bfloat16(w_final[i]);
}

// Kernel 3: fused outer-product GEMM (128x128 tile, K=512) + w_final projection epilogue.
// Block = 256 threads = 4 waves in 2x2; each wave owns a 64x64 quadrant (4x4 MFMA tiles).
// K-loop is now DOUBLE-BUFFERED (2-phase): stage(kt+1) is issued before compute(kt),
// and the single __syncthreads per iter drains it ~compute-phase cycles later,
// hiding the global->LDS latency that the previous version exposed every step.
__global__ __launch_bounds__(256, 2) void fused_opm(
    const __hip_bfloat16* __restrict__ Abt, const __hip_bfloat16* __restrict__ Bbt,
    const __hip_bfloat16* __restrict__ Wf, const float* __restrict__ b_final,
    float* __restrict__ out) {
  // Main phase: two buffers, each As[128][32] + Bs[128][32] bf16 (16 KB) -> 32 KB.
  // Epilogue:  Oc[16][1032] bf16 (33 KB, padded stride breaks bank conflicts).
  // The epilogue allocation (33024 B) already covers the 32768 B double buffer.
  __shared__ __align__(16) char smem[16 * 1032 * 2];

  const int tid = threadIdx.x;
  const int wave = tid >> 6;
  const int lane = tid & 63;
  const int fr = lane & 15;  // MFMA row/col-within-tile index
  const int fq = lane >> 4;  // MFMA quad index
  const int wr = wave >> 1, wc = wave & 1;
  const int bi = blockIdx.y, bj = blockIdx.x;

  const size_t m0 = (size_t)bi * 128;
  const size_t n0 = (size_t)bj * 128;

  // Staging: 8192 B per matrix per K-step = 2 issues of 256 lanes x 16 B.
  // LDS dest is wave-uniform base + lane*16 -> As row-major [row][k], no padding.
  const int srow = tid >> 2;        // 0..63 (chunk 1 adds +64)
  const int sk = (tid & 3) * 8;     // k element offset within row
  const __hip_bfloat16* gA = Abt + (m0 + srow) * N_DIM + sk;
  const __hip_bfloat16* gB = Bbt + (n0 + srow) * N_DIM + sk;
  const int ldst = tid * 16;

  const f32x4 fzero = {0.f, 0.f, 0.f, 0.f};
  f32x4 acc[4][4];
#pragma unroll
  for (int i = 0; i < 4; ++i)
#pragma unroll
    for (int j = 0; j < 4; ++j) acc[i][j] = fzero;

  // Issue the 4 global_load_lds for K-tile kt into buffer `base`.
  auto stage = [&](int kt, char* base) {
    const int k0 = kt * 32;
    async16(gA + k0, base + ldst);
    async16(gA + (size_t)64 * N_DIM + k0, base + 4096 + ldst);
    async16(gB + k0, base + 8192 + ldst);
    async16(gB + (size_t)64 * N_DIM + k0, base + 12288 + ldst);
  };

  // ds_read fragments + 16 MFMA from buffer `base`.
  auto compute = [&](const char* base) {
    const __hip_bfloat16* As = (const __hip_bfloat16*)base;
    const __hip_bfloat16* Bs = (const __hip_bfloat16*)(base + 8192);
    short8 af[4], bfr[4];
#pragma unroll
    for (int mt = 0; mt < 4; ++mt)
      af[mt] = *(const short8*)(As + (wr * 64 + mt * 16 + fr) * 32 + fq * 8);
#pragma unroll
    for (int nt = 0; nt < 4; ++nt)
      bfr[nt] = *(const short8*)(Bs + (wc * 64 + nt * 16 + fr) * 32 + fq * 8);
#pragma unroll
    for (int mt = 0; mt < 4; ++mt)
#pragma unroll
      for (int nt = 0; nt < 4; ++nt)
        acc[mt][nt] = __builtin_amdgcn_mfma_f32_16x16x32_bf16(
            af[mt], bfr[nt], acc[mt][nt], 0, 0, 0);
  };

  char* buf0 = smem;
  char* buf1 = smem + 16384;

  // Prologue: fill buf0.
  stage(0, buf0);
  __syncthreads();  // vmcnt(0) drain: tile 0 resident

  // Steady state, unrolled x2 so buffer bases are compile-time.
  for (int kt = 0; kt < 16; kt += 2) {
    stage(kt + 1, buf1);    // prefetch next tile (latency hidden by compute)
    compute(buf0);
    __syncthreads();        // drains vmcnt: tile kt+1 resident; buf0 reads done
    if (kt + 2 < 16) stage(kt + 2, buf0);
    compute(buf1);
    __syncthreads();
  }

  // ---- Epilogue phase 1: o-tile (fp32 acc) -> Oc LDS bf16 [cell][c*32+d] ----
  // (final K-loop __syncthreads already ensures all waves are done with As/Bs)
  __hip_bfloat16* Oc = (__hip_bfloat16*)smem;  // [16][1032]
#pragma unroll
  for (int mt = 0; mt < 4; ++mt) {
#pragma unroll
    for (int nt = 0; nt < 4; ++nt) {
      const int orow_b = wr * 64 + mt * 16 + fq * 4;
      const int ocol = wc * 64 + nt * 16 + fr;  // C/D map: col=lane&15
#pragma unroll
      for (int r = 0; r < 4; ++r) {             // row=(lane>>4)*4+reg
        const int orow = orow_b + r;
        const int cell = ((orow >> 5) << 2) + (ocol >> 5);  // li*4+lj
        const int kk = ((orow & 31) << 5) + (ocol & 31);    // c*32+d
        Oc[cell * 1032 + kk] = __float2bfloat16(acc[mt][nt][r]);
      }
    }
  }
  __syncthreads();

  // ---- Epilogue phase 2: Z[16 cells][128] = Oc[16][1024] @ Wf[128][1024]^T ----
  // Each wave takes 2 of the 8 z-tiles (16 cols each); K-loop 32 steps of 32.
  f32x4 zacc0 = fzero, zacc1 = fzero;
  const int zt0 = wave * 2;
  for (int kk = 0; kk < 32; ++kk) {
    const short8 oa = *(const short8*)(Oc + fr * 1032 + kk * 32 + fq * 8);
    const short8 wb0 =
        *(const short8*)(Wf + (size_t)((zt0 + 0) * 16 + fr) * 1024 + kk * 32 + fq * 8);
    const short8 wb1 =
        *(const short8*)(Wf + (size_t)((zt0 + 1) * 16 + fr) * 1024 + kk * 32 + fq * 8);
    zacc0 = __builtin_amdgcn_mfma_f32_16x16x32_bf16(oa, wb0, zacc0, 0, 0, 0);
    zacc1 = __builtin_amdgcn_mfma_f32_16x16x32_bf16(oa, wb1, zacc1, 0, 0, 0);
  }

  // ---- Epilogue phase 3: z-write (+ b_final) ----
  const int i0 = bi * 4, j0 = bj * 4;
#pragma unroll
  for (int t = 0; t < 2; ++t) {
    const int zcol = (zt0 + t) * 16 + fr;
    const float bz = b_final[zcol];
    const f32x4 za = t ? zacc1 : zacc0;
#pragma unroll
    for (int r = 0; r < 4; ++r) {
      const int cell = fq * 4 + r;  // D row = cell index
      const int li = cell >> 2, lj = cell & 3;
      out[((size_t)(i0 + li) * S_DIM + (j0 + lj)) * CZ_DIM + zcol] = za[r] + bz;
    }
  }
}

extern "C" void kernel_launch(void* const* d_in, const int* in_sizes, int n_in,
                              void* d_out, int out_size, void* d_ws, size_t ws_size,
                              hipStream_t stream) {
  const float* m_si = (const float*)d_in[0];
  const float* ln_g = (const float*)d_in[1];
  const float* ln_b = (const float*)d_in[2];
  const float* w_ab = (const float*)d_in[3];
  const float* w_final = (const float*)d_in[4];
  const float* b_final = (const float*)d_in[5];
  float* out = (float*)d_out;

  char* ws = (char*)d_ws;
  __hip_bfloat16* Abt = (__hip_bfloat16*)ws;                                // 12.58 MB
  __hip_bfloat16* Bbt = (__hip_bfloat16*)(ws + (size_t)MROWS * N_DIM * 2);  // 12.58 MB
  __hip_bfloat16* Wf = (__hip_bfloat16*)(ws + (size_t)MROWS * N_DIM * 4);   // 256 KB

  prep_kernel<<<dim3(2, S_DIM), 256, 0, stream>>>(m_si, ln_g, ln_b, w_ab, Abt, Bbt);
  conv_wf<<<dim3((CZ_DIM * 1024) / 256), 256, 0, stream>>>(w_final, Wf);
  fused_opm<<<dim3(96, 96), 256, 0, stream>>>(Abt, Bbt, Wf, b_final, out);
}